// Round 1
// baseline (4831.971 us; speedup 1.0000x reference)
//
#include <hip/hip_runtime.h>
#include <math.h>

#define BB 4
#define TT 10
#define NN 4096
#define HH 32
#define JC 132                 // B*(H+1)
#define NJ (NN*JC)             // 540672
#define CSZ (TT*NJ)            // 5406720
#define NH (NN*HH)             // 131072

// ---------- kernel 1: build C1[t][n][j],  j = b*33 + kk ; kk==0 -> x, else h ----------
__global__ void k_build_c1(const float* __restrict__ inp, const float* __restrict__ st,
                           float* __restrict__ C) {
    int e = blockIdx.x * 256 + threadIdx.x;
    if (e >= CSZ) return;
    int j = e % JC;
    int rem = e / JC;
    int n = rem % NN;
    int t = rem / NN;
    int b = j / 33, kk = j - b * 33;
    float v;
    if (kk == 0) {
        v = inp[(b * TT + t) * NN + n];
    } else {
        int jj = n * HH + (kk - 1);
        v = st[(t * BB + b) * NH + jj];
    }
    C[e] = v;
}

// ---------- kernel 2/6: fused A-construction GEMM:  Out[t][m][j] = sum_n A_t[m,n]*C[t][n][j] ----------
__global__ __launch_bounds__(256) void k_conv(const float* __restrict__ dtw,
                                              const float* __restrict__ tdl,
                                              const float* __restrict__ spl,
                                              const float* __restrict__ lap,
                                              const float* __restrict__ C,
                                              float* __restrict__ Out) {
    int t = blockIdx.z;
    int m0 = blockIdx.x * 64;
    int tid = threadIdx.x;
    int tx = tid & 31, ty = tid >> 5;
    bool last = (t == TT - 1);
    float tf1 = (float)t + 1.0f;
    float scale = last ? (1.0f / 3.0f) : 0.5f;

    __shared__ float wA[32 * 65];     // [n_local][m_local], padded
    __shared__ float cS[32 * JC];     // [n_local][j]

    float acc[8][5];
#pragma unroll
    for (int i = 0; i < 8; i++)
#pragma unroll
        for (int j = 0; j < 5; j++) acc[i][j] = 0.f;

    for (int kb = 0; kb < NN; kb += 32) {
        // stage A_t tile: 64 m x 32 n, built on the fly from components
#pragma unroll
        for (int i = 0; i < 8; i++) {
            int l = tid + 256 * i;             // 2048 elements
            int ml = l >> 5, nl = l & 31;
            int gm = m0 + ml, gn = kb + nl;
            int gi = gm * NN + gn;
            float d = dtw[gi];
            float td = tdl[gi];
            float sl = spl[gi];
            float ti = 10.0f - ceilf(fabsf(td));
            float don = (d != 0.0f && tf1 > ti) ? d : 0.0f;
            float w = don + sl + ((gm == gn) ? 1.0f : 0.0f);
            if (last) w += lap[gi];
            wA[nl * 65 + ml] = w * scale;
        }
        // stage C tile: 32 n x 132 j (132/4 = 33 float4 per row)
        for (int l4 = tid; l4 < 32 * 33; l4 += 256) {
            int nl = l4 / 33, j4 = l4 - nl * 33;
            float4 v = ((const float4*)(C + (size_t)(t * NN + kb + nl) * JC))[j4];
            ((float4*)(cS + nl * JC))[j4] = v;
        }
        __syncthreads();
#pragma unroll 8
        for (int n = 0; n < 32; n++) {
            float cv[5];
#pragma unroll
            for (int jj = 0; jj < 5; jj++) {
                int j = tx + 32 * jj;
                cv[jj] = (j < JC) ? cS[n * JC + j] : 0.f;
            }
            float wv[8];
#pragma unroll
            for (int mi = 0; mi < 8; mi++) wv[mi] = wA[n * 65 + ty * 8 + mi];
#pragma unroll
            for (int mi = 0; mi < 8; mi++)
#pragma unroll
                for (int jj = 0; jj < 5; jj++)
                    acc[mi][jj] = fmaf(wv[mi], cv[jj], acc[mi][jj]);
        }
        __syncthreads();
    }
    for (int mi = 0; mi < 8; mi++) {
        int m = m0 + ty * 8 + mi;
        for (int jj = 0; jj < 5; jj++) {
            int j = tx + 32 * jj;
            if (j < JC) Out[(size_t)(t * NN + m) * JC + j] = acc[mi][jj];
        }
    }
}

// ---------- kernel 3: in-place prefix sum over t ----------
__global__ void k_prefix(float* __restrict__ M) {
    int e = blockIdx.x * 256 + threadIdx.x;
    if (e >= NJ) return;
    float run = 0.f;
#pragma unroll
    for (int t = 0; t < TT; t++) {
        run += M[(size_t)t * NJ + e];
        M[(size_t)t * NJ + e] = run;
    }
}

// ---------- kernel 4: gcn1[t][b][m][q] = (t+1)*b1[q] + sum_kk P[t][m][b*33+kk]*W1[kk][q] ----------
__global__ __launch_bounds__(256) void k_gcn1(const float* __restrict__ P,
                                              const float* __restrict__ W1,
                                              const float* __restrict__ b1,
                                              float* __restrict__ G) {
    int m0 = blockIdx.x * 32;
    int b = blockIdx.y, t = blockIdx.z;
    int tid = threadIdx.x;
    __shared__ float Ws[33 * 64];
    __shared__ float Ps[32 * 33];
    for (int l = tid; l < 33 * 64; l += 256) Ws[l] = W1[l];
    for (int l = tid; l < 32 * 33; l += 256) {
        int mr = l / 33, kk = l - mr * 33;
        Ps[l] = P[(size_t)(t * NN + m0 + mr) * JC + b * 33 + kk];
    }
    __syncthreads();
    int q = tid & 63, ms = tid >> 6;
    float bias = (float)(t + 1) * b1[q];
    for (int mi = 0; mi < 8; mi++) {
        int ml = ms * 8 + mi;
        float a = bias;
#pragma unroll
        for (int kk = 0; kk < 33; kk++) a = fmaf(Ps[ml * 33 + kk], Ws[kk * 64 + q], a);
        G[(size_t)((t * BB + b) * NN + m0 + ml) * 64 + q] = a;
    }
}

// ---------- kernel 5: build C2[t][n][j];  r flat-split quirk handled here ----------
__global__ void k_build_c2(const float* __restrict__ inp, const float* __restrict__ st,
                           const float* __restrict__ G, float* __restrict__ C) {
    int e = blockIdx.x * 256 + threadIdx.x;
    if (e >= CSZ) return;
    int j = e % JC;
    int rem = e / JC;
    int n = rem % NN;
    int t = rem / NN;
    int b = j / 33, kk = j - b * 33;
    float v;
    if (kk == 0) {
        v = inp[(b * TT + t) * NN + n];
    } else {
        int jj = n * HH + (kk - 1);                     // flat [N*H] index
        // r_flat[b][jj] = sigmoid(gcn1_t flat jj): node jj>>6, channel jj&63
        float g = G[(size_t)((t * BB + b) * NN + (jj >> 6)) * 64 + (jj & 63)];
        float r = 1.0f / (1.0f + expf(-g));
        v = r * st[(t * BB + b) * NH + jj];
    }
    C[e] = v;
}

// ---------- kernel 7: reduce M2 over t ----------
__global__ void k_reduce(const float* __restrict__ M, float* __restrict__ S) {
    int e = blockIdx.x * 256 + threadIdx.x;
    if (e >= NJ) return;
    float s = 0.f;
#pragma unroll
    for (int t = 0; t < TT; t++) s += M[(size_t)t * NJ + e];
    S[e] = s;
}

// ---------- kernel 8: epilogue: gcn2@W2 + bias, tanh, u-gate, output ----------
__global__ __launch_bounds__(256) void k_final(const float* __restrict__ S,
                                               const float* __restrict__ G,
                                               const float* __restrict__ st,
                                               const float* __restrict__ W2,
                                               const float* __restrict__ b2,
                                               float* __restrict__ out) {
    __shared__ float Ws[33 * 32];
    int tid = threadIdx.x;
    for (int l = tid; l < 33 * 32; l += 256) Ws[l] = W2[l];
    __syncthreads();
    int e = blockIdx.x * 256 + tid;        // over B*N*H = 524288
    int b = e >> 17;
    int jj = e & (NH - 1);
    int m = jj >> 5, q = jj & 31;
    float a = 10.0f * b2[q];
#pragma unroll
    for (int kk = 0; kk < 33; kk++) a = fmaf(S[m * JC + b * 33 + kk], Ws[kk * 32 + q], a);
    float c = tanhf(a);
    // u_flat[b][jj] = sigmoid(gcn1_9 flat [131072+jj]): node 2048 + jj>>6, channel jj&63
    float gu = G[(size_t)((9 * BB + b) * NN + 2048 + (jj >> 6)) * 64 + (jj & 63)];
    float u = 1.0f / (1.0f + expf(-gu));
    float h = st[(9 * BB + b) * NH + jj];
    out[e] = u * h + (1.0f - u) * c;
}

extern "C" void kernel_launch(void* const* d_in, const int* in_sizes, int n_in,
                              void* d_out, int out_size, void* d_ws, size_t ws_size,
                              hipStream_t stream) {
    const float* inp = (const float*)d_in[0];
    const float* st  = (const float*)d_in[1];
    const float* dtw = (const float*)d_in[2];
    const float* spl = (const float*)d_in[3];
    const float* lap = (const float*)d_in[4];
    const float* tdl = (const float*)d_in[5];
    const float* W1  = (const float*)d_in[6];
    const float* b1  = (const float*)d_in[7];
    const float* W2  = (const float*)d_in[8];
    const float* b2  = (const float*)d_in[9];
    float* out = (float*)d_out;

    float* ws = (float*)d_ws;
    float* bufC = ws;                  // CSZ floats: C1, later C2; first NJ reused for M2-sum
    float* bufM = ws + CSZ;            // CSZ floats: M1 -> P1 (in place) -> M2 per-t
    float* bufG = ws + 2 * (size_t)CSZ; // 10*B*N*64 floats: gcn1 raw

    k_build_c1<<<(CSZ + 255) / 256, 256, 0, stream>>>(inp, st, bufC);

    dim3 gconv(NN / 64, 1, TT);
    k_conv<<<gconv, 256, 0, stream>>>(dtw, tdl, spl, lap, bufC, bufM);   // pass 1

    k_prefix<<<(NJ + 255) / 256, 256, 0, stream>>>(bufM);

    dim3 ggcn(NN / 32, BB, TT);
    k_gcn1<<<ggcn, 256, 0, stream>>>(bufM, W1, b1, bufG);

    k_build_c2<<<(CSZ + 255) / 256, 256, 0, stream>>>(inp, st, bufG, bufC);

    k_conv<<<gconv, 256, 0, stream>>>(dtw, tdl, spl, lap, bufC, bufM);   // pass 2

    k_reduce<<<(NJ + 255) / 256, 256, 0, stream>>>(bufM, bufC);          // M2 sum -> bufC[0:NJ)

    k_final<<<(BB * NN * HH) / 256, 256, 0, stream>>>(bufC, bufG, st, W2, b2, out);
}

// Round 3
// 639.729 us; speedup vs baseline: 7.5532x; 7.5532x over previous
//
#include <hip/hip_runtime.h>
#include <math.h>

#define BB 4
#define TT 10
#define NN 4096
#define HH 32
#define JP 144                    // padded j (132 real: 4 b * 33 kk)
#define NJ2 (NN*JP)               // 589824
#define NH (NN*HH)                // 131072
#define NPAIR (NN*NN/2)           // 8388608 (fp16 pairs / u32 words)

typedef __attribute__((ext_vector_type(8))) short short8;
typedef __attribute__((ext_vector_type(8))) _Float16 half8;
typedef __attribute__((ext_vector_type(4))) float floatx4;
typedef __attribute__((ext_vector_type(4))) unsigned int uintx4;
typedef __attribute__((ext_vector_type(2))) unsigned int uintx2;

__device__ inline unsigned short f2h(float f) {
    _Float16 h = (_Float16)f;                  // v_cvt_f16_f32, RNE
    unsigned short u; __builtin_memcpy(&u, &h, 2);
    return u;
}
__device__ inline unsigned pk2(float a, float b) {
    return (unsigned)f2h(a) | ((unsigned)f2h(b) << 16);
}

// ---------- prep: pack A_off=spl+I, A_on=off+dtw, A9=off+masked dtw+lap, thr u8 ----------
__global__ void k_pack(const float* __restrict__ dtw, const float* __restrict__ tdl,
                       const float* __restrict__ spl, const float* __restrict__ lap,
                       unsigned* __restrict__ Aoff, unsigned* __restrict__ Aon,
                       unsigned* __restrict__ A9, unsigned short* __restrict__ thr2) {
    int e = blockIdx.x * 256 + threadIdx.x;          // pair index
    if (e >= NPAIR) return;
    size_t gi = (size_t)e * 2;
    int row = (int)(gi >> 12);
    int c0 = (int)(gi & 4095);
    float2 d = ((const float2*)dtw)[e];
    float2 td = ((const float2*)tdl)[e];
    float2 s = ((const float2*)spl)[e];
    float2 l = ((const float2*)lap)[e];
    float td0 = ceilf(fabsf(td.x)), td1 = ceilf(fabsf(td.y));
    int th0 = 10 - (int)td0; if (th0 < 0) th0 = 0;
    int th1 = 10 - (int)td1; if (th1 < 0) th1 = 0;
    float off0 = s.x + ((row == c0) ? 1.f : 0.f);
    float off1 = s.y + ((row == c0 + 1) ? 1.f : 0.f);
    float on0 = off0 + d.x, on1 = off1 + d.y;
    // t=9 mask: t+1=10 > 10-td_c  <=>  td_c>0 ; plus dtw!=0 exactness
    float a90 = off0 + l.x + ((td0 > 0.f && d.x != 0.f) ? d.x : 0.f);
    float a91 = off1 + l.y + ((td1 > 0.f && d.y != 0.f) ? d.y : 0.f);
    Aoff[e] = pk2(off0, off1);
    Aon[e]  = pk2(on0, on1);
    A9[e]   = pk2(a90, a91);
    thr2[e] = (unsigned short)(th0 | (th1 << 8));
}

// ---------- zero the pad rows j in [132,144) of Ct (ws is poisoned every launch) ----------
__global__ void k_zpad(unsigned short* __restrict__ Ct) {
    int e = blockIdx.x * 256 + threadIdx.x;          // over 10*12*4096
    if (e >= TT * 12 * NN) return;
    int n = e & 4095;
    int r = e >> 12;
    int t = r / 12, j = 132 + (r % 12);
    Ct[(size_t)(t * JP + j) * NN + n] = 0;
}

// ---------- build Ct[t][j][n] fp16, scale folded; pass1 (h raw) ----------
__global__ void k_build_ct1(const float* __restrict__ inp, const float* __restrict__ st,
                            unsigned short* __restrict__ Ct) {
    int nb = blockIdx.x, b = blockIdx.y, t = blockIdx.z;
    int tid = threadIdx.x;
    float sc = (t == TT - 1) ? (1.f / 3.f) : 0.5f;
    int kk = tid & 31;          // channel 0..31 -> j = b*33 + 1 + kk
    int ng = tid >> 5;          // 0..7
    const float* stb = st + (size_t)(t * BB + b) * NH;
    unsigned short* crow = Ct + (size_t)(t * JP + b * 33 + 1 + kk) * NN;
    int n0 = nb * 128 + ng * 16;
#pragma unroll
    for (int i = 0; i < 16; i++) {
        int n = n0 + i;
        crow[n] = f2h(stb[n * 32 + kk] * sc);       // coalesced read across kk
    }
    if (tid < 128) {            // x row: j = b*33
        int n = nb * 128 + tid;
        Ct[(size_t)(t * JP + b * 33) * NN + n] = f2h(inp[((size_t)b * TT + t) * NN + n] * sc);
    }
}

// ---------- build Ct pass2: h replaced by r*h, r = sigmoid(gcn1 flat) ----------
__global__ void k_build_ct2(const float* __restrict__ inp, const float* __restrict__ st,
                            const float* __restrict__ G, unsigned short* __restrict__ Ct) {
    int nb = blockIdx.x, b = blockIdx.y, t = blockIdx.z;
    int tid = threadIdx.x;
    float sc = (t == TT - 1) ? (1.f / 3.f) : 0.5f;
    int kk = tid & 31;
    int ng = tid >> 5;
    const float* stb = st + (size_t)(t * BB + b) * NH;
    const float* Gb = G + (size_t)(t * BB + b) * NN * 64;   // flat index == jj
    unsigned short* crow = Ct + (size_t)(t * JP + b * 33 + 1 + kk) * NN;
    int n0 = nb * 128 + ng * 16;
#pragma unroll
    for (int i = 0; i < 16; i++) {
        int n = n0 + i;
        int jj = n * 32 + kk;
        float g = Gb[jj];
        float r = 1.0f / (1.0f + expf(-g));
        crow[n] = f2h(r * stb[jj] * sc);
    }
    if (tid < 128) {
        int n = nb * 128 + tid;
        Ct[(size_t)(t * JP + b * 33) * NN + n] = f2h(inp[((size_t)b * TT + t) * NN + n] * sc);
    }
}

// ---------- MFMA GEMM: Out[ks][t][m][j] = sum_{k in split} A_t[m,k] * C_t[k,j] ----------
__global__ __launch_bounds__(256) void k_mfma(const unsigned* __restrict__ Aoff,
                                              const unsigned* __restrict__ Aon,
                                              const unsigned* __restrict__ A9,
                                              const unsigned short* __restrict__ thr2,
                                              const unsigned* __restrict__ Ct,
                                              float* __restrict__ Out) {
    int t = blockIdx.z;
    int ks = blockIdx.y;
    int m0 = blockIdx.x * 128;
    int k0 = ks * 2048;
    int tid = threadIdx.x;
    int w = tid >> 6, lane = tid & 63;
    int lm = lane & 15, q = lane >> 4;

    __shared__ short As[128 * 40];     // row stride 40 shorts (80B = 5*16B, dodges bank conflicts)
    __shared__ short Cs[JP * 40];
    unsigned* Asu = (unsigned*)As;
    unsigned* Csu = (unsigned*)Cs;

    floatx4 acc[2][9];
#pragma unroll
    for (int i = 0; i < 2; i++)
#pragma unroll
        for (int j = 0; j < 9; j++) acc[i][j] = (floatx4){0.f, 0.f, 0.f, 0.f};

    bool last = (t == TT - 1);

    for (int kb = 0; kb < 2048; kb += 32) {
        size_t kc = (size_t)(k0 + kb) >> 1;          // u32 col base within a row
        // ---- stage A: 128 rows x 16 u32  = 512 uint4 items, 2 per thread
#pragma unroll
        for (int it = 0; it < 2; it++) {
            int l = tid + 256 * it;
            int row = l >> 2, c4 = (l & 3) * 4;
            size_t g = (size_t)(m0 + row) * 2048 + kc + c4;
            uintx4 res;
            if (last) {
                res = *(const uintx4*)(A9 + g);
            } else {
                uintx4 o4 = *(const uintx4*)(Aoff + g);
                uintx4 a4 = *(const uintx4*)(Aon + g);
                uintx2 th2 = *(const uintx2*)(thr2 + g);   // 4 u16 thresholds
#pragma unroll
                for (int u = 0; u < 4; u++) {
                    unsigned th = (u < 2) ? (th2[0] >> ((u & 1) * 16)) : (th2[1] >> ((u & 1) * 16));
                    th &= 0xFFFFu;
                    unsigned lo = ((int)(th & 255u) <= t) ? a4[u] : o4[u];
                    unsigned hi = ((int)(th >> 8) <= t) ? a4[u] : o4[u];
                    res[u] = (lo & 0xFFFFu) | (hi & 0xFFFF0000u);
                }
            }
            *(uintx4*)(Asu + row * 20 + c4) = res;
        }
        // ---- stage C: 144 rows x 16 u32 = 576 uint4 items
        for (int l = tid; l < 576; l += 256) {
            int j = l >> 2, c4 = (l & 3) * 4;
            size_t g = (size_t)(t * JP + j) * 2048 + kc + c4;
            *(uintx4*)(Csu + j * 20 + c4) = *(const uintx4*)(Ct + g);
        }
        __syncthreads();
        // ---- fragments + MFMA: wave w -> rows [w*32, w*32+32), all 9 j-tiles
        short8 a0 = *(const short8*)(As + (w * 32 + lm) * 40 + q * 8);
        short8 a1 = *(const short8*)(As + (w * 32 + 16 + lm) * 40 + q * 8);
        half8 ah0 = __builtin_bit_cast(half8, a0);
        half8 ah1 = __builtin_bit_cast(half8, a1);
#pragma unroll
        for (int jt = 0; jt < 9; jt++) {
            short8 bv = *(const short8*)(Cs + (jt * 16 + lm) * 40 + q * 8);
            half8 bh = __builtin_bit_cast(half8, bv);
            acc[0][jt] = __builtin_amdgcn_mfma_f32_16x16x32_f16(ah0, bh, acc[0][jt], 0, 0, 0);
            acc[1][jt] = __builtin_amdgcn_mfma_f32_16x16x32_f16(ah1, bh, acc[1][jt], 0, 0, 0);
        }
        __syncthreads();
    }
    // ---- epilogue: C/D layout col=lane&15, row=(lane>>4)*4+r
    float* Ob = Out + ((size_t)ks * TT + t) * (size_t)NN * JP;
#pragma unroll
    for (int mt = 0; mt < 2; mt++) {
        int row = m0 + w * 32 + mt * 16 + q * 4;
#pragma unroll
        for (int jt = 0; jt < 9; jt++) {
            int col = jt * 16 + lm;
#pragma unroll
            for (int r = 0; r < 4; r++)
                Ob[(size_t)(row + r) * JP + col] = acc[mt][jt][r];
        }
    }
}

// ---------- prefix sum over t (reads both k-splits, writes prefix into O0) ----------
__global__ void k_prefix(float* __restrict__ O0, const float* __restrict__ O1) {
    int e = blockIdx.x * 256 + threadIdx.x;
    if (e >= NJ2) return;
    float run = 0.f;
#pragma unroll
    for (int t = 0; t < TT; t++) {
        run += O0[(size_t)t * NJ2 + e] + O1[(size_t)t * NJ2 + e];
        O0[(size_t)t * NJ2 + e] = run;
    }
}

// ---------- gcn1[t][b][m][q] = (t+1)*b1[q] + sum_kk P[t][m][b*33+kk]*W1[kk][q] ----------
__global__ __launch_bounds__(256) void k_gcn1(const float* __restrict__ P,
                                              const float* __restrict__ W1,
                                              const float* __restrict__ b1,
                                              float* __restrict__ G) {
    int m0 = blockIdx.x * 32;
    int b = blockIdx.y, t = blockIdx.z;
    int tid = threadIdx.x;
    __shared__ float Ws[33 * 64];
    __shared__ float Ps[32 * 33];
    for (int l = tid; l < 33 * 64; l += 256) Ws[l] = W1[l];
    for (int l = tid; l < 32 * 33; l += 256) {
        int mr = l / 33, kk = l - mr * 33;
        Ps[l] = P[(size_t)(t * NN + m0 + mr) * JP + b * 33 + kk];
    }
    __syncthreads();
    int qq = tid & 63, ms = tid >> 6;
    float bias = (float)(t + 1) * b1[qq];
    for (int mi = 0; mi < 8; mi++) {
        int ml = ms * 8 + mi;
        float a = bias;
#pragma unroll
        for (int kk = 0; kk < 33; kk++) a = fmaf(Ps[ml * 33 + kk], Ws[kk * 64 + qq], a);
        G[(size_t)((t * BB + b) * NN + m0 + ml) * 64 + qq] = a;
    }
}

// ---------- reduce over t (both splits) -> S[m][JP] ----------
__global__ void k_reduce(const float* __restrict__ O0, const float* __restrict__ O1,
                         float* __restrict__ S) {
    int e = blockIdx.x * 256 + threadIdx.x;
    if (e >= NJ2) return;
    float s = 0.f;
#pragma unroll
    for (int t = 0; t < TT; t++)
        s += O0[(size_t)t * NJ2 + e] + O1[(size_t)t * NJ2 + e];
    S[e] = s;
}

// ---------- epilogue: gcn2@W2 + bias, tanh, u-gate ----------
__global__ __launch_bounds__(256) void k_final(const float* __restrict__ S,
                                               const float* __restrict__ G,
                                               const float* __restrict__ st,
                                               const float* __restrict__ W2,
                                               const float* __restrict__ b2,
                                               float* __restrict__ out) {
    __shared__ float Ws[33 * 32];
    int tid = threadIdx.x;
    for (int l = tid; l < 33 * 32; l += 256) Ws[l] = W2[l];
    __syncthreads();
    int e = blockIdx.x * 256 + tid;        // over B*N*H
    int b = e >> 17;
    int jj = e & (NH - 1);
    int m = jj >> 5, q = jj & 31;
    float a = 10.0f * b2[q];
#pragma unroll
    for (int kk = 0; kk < 33; kk++) a = fmaf(S[m * JP + b * 33 + kk], Ws[kk * 32 + q], a);
    float c = tanhf(a);
    float gu = G[(size_t)((9 * BB + b) * NN + 2048 + (jj >> 6)) * 64 + (jj & 63)];
    float u = 1.0f / (1.0f + expf(-gu));
    float h = st[(size_t)(9 * BB + b) * NH + jj];
    out[e] = u * h + (1.0f - u) * c;
}

extern "C" void kernel_launch(void* const* d_in, const int* in_sizes, int n_in,
                              void* d_out, int out_size, void* d_ws, size_t ws_size,
                              hipStream_t stream) {
    const float* inp = (const float*)d_in[0];
    const float* st  = (const float*)d_in[1];
    const float* dtw = (const float*)d_in[2];
    const float* spl = (const float*)d_in[3];
    const float* lap = (const float*)d_in[4];
    const float* tdl = (const float*)d_in[5];
    const float* W1  = (const float*)d_in[6];
    const float* b1  = (const float*)d_in[7];
    const float* W2  = (const float*)d_in[8];
    const float* b2  = (const float*)d_in[9];
    float* out = (float*)d_out;

    char* W = (char*)d_ws;
    unsigned*       Aoff = (unsigned*)W;                     W += (size_t)NPAIR * 4;
    unsigned*       Aon  = (unsigned*)W;                     W += (size_t)NPAIR * 4;
    unsigned*       A9   = (unsigned*)W;                     W += (size_t)NPAIR * 4;
    unsigned short* thr2 = (unsigned short*)W;               W += (size_t)NPAIR * 2;
    unsigned short* Ct   = (unsigned short*)W;               W += (size_t)TT * JP * NN * 2;
    float*          O    = (float*)W;                        W += (size_t)2 * TT * NJ2 * 4;
    float*          G    = (float*)W;                        W += (size_t)TT * BB * NN * 64 * 4;
    float*          S    = (float*)W;                        W += (size_t)NJ2 * 4;
    float* O1 = O + (size_t)TT * NJ2;

    k_pack<<<NPAIR / 256, 256, 0, stream>>>(dtw, tdl, spl, lap, Aoff, Aon, A9, thr2);
    k_zpad<<<(TT * 12 * NN + 255) / 256, 256, 0, stream>>>(Ct);

    dim3 gbld(NN / 128, BB, TT);
    k_build_ct1<<<gbld, 256, 0, stream>>>(inp, st, Ct);

    dim3 gmm(NN / 128, 2, TT);
    k_mfma<<<gmm, 256, 0, stream>>>(Aoff, Aon, A9, thr2, (const unsigned*)Ct, O);   // pass 1

    k_prefix<<<NJ2 / 256, 256, 0, stream>>>(O, O1);

    dim3 ggcn(NN / 32, BB, TT);
    k_gcn1<<<ggcn, 256, 0, stream>>>(O, W1, b1, G);

    k_build_ct2<<<gbld, 256, 0, stream>>>(inp, st, G, Ct);

    k_mfma<<<gmm, 256, 0, stream>>>(Aoff, Aon, A9, thr2, (const unsigned*)Ct, O);   // pass 2

    k_reduce<<<NJ2 / 256, 256, 0, stream>>>(O, O1, S);

    k_final<<<(BB * NN * HH) / 256, 256, 0, stream>>>(S, G, st, W2, b2, out);
}